// Round 15
// baseline (237.563 us; speedup 1.0000x reference)
//
#include <hip/hip_runtime.h>
#include <math.h>

#define TPB 256

typedef __attribute__((ext_vector_type(8))) short s16x8;
typedef __attribute__((ext_vector_type(4))) short s16x4;
typedef __attribute__((ext_vector_type(4))) float f32x4;
typedef unsigned int u32;

constexpr int Bn = 64, Kc = 24, TSz = 11;
constexpr int NBK = Bn * Kc;          // 1536

// ---- workspace offsets (BYTES) ----
constexpr size_t SZW_B    = (size_t)Kc * 36 * 4096 * 2;      // 7,077,888 B/plane
constexpr size_t OFFB_W2  = 0;
constexpr size_t OFFB_W3  = OFFB_W2 + SZW_B;
constexpr size_t OFFB_W4  = OFFB_W3 + SZW_B;
constexpr size_t OFFB_DMV = OFFB_W4 + SZW_B;
constexpr size_t OFFB_TT  = OFFB_DMV + (size_t)NBK * 4;
constexpr size_t OFFB_ST  = OFFB_TT + (size_t)NBK * 1600 * 4;
constexpr size_t OFFB_MXS = OFFB_ST + 512;
constexpr size_t OFFB_PART= OFFB_MXS + (size_t)NBK * 2 * 4;

// ---- output offsets (floats) ----
constexpr int OUT_OC = 1;                   // input_ocae [B,K,136]
constexpr int OUT_XM = 1 + NBK * 136;
constexpr int OUT_DM = OUT_XM + NBK * 6;

// ============ bf16 helpers ============
__device__ __forceinline__ ushort f2b(float f) {
    union { float f; unsigned u; } c; c.f = f;
    unsigned r = c.u + 0x7fffu + ((c.u >> 16) & 1u);
    return (ushort)(r >> 16);
}
__device__ __forceinline__ float b2f(ushort h) {
    union { unsigned u; float f; } c; c.u = ((unsigned)h) << 16; return c.f;
}

// ============ reductions ============
__device__ __forceinline__ float blockReduceSum(float v) {     // 256 threads
    __shared__ float red[4];
    __syncthreads();
#pragma unroll
    for (int o = 32; o > 0; o >>= 1) v += __shfl_down(v, o, 64);
    int lane = threadIdx.x & 63, wv = threadIdx.x >> 6;
    if (lane == 0) red[wv] = v;
    __syncthreads();
    return red[0] + red[1] + red[2] + red[3];
}

__device__ __forceinline__ float blockReduceSum512(float v) {  // 512 threads
    __shared__ float red8[8];
    __syncthreads();
#pragma unroll
    for (int o = 32; o > 0; o >>= 1) v += __shfl_down(v, o, 64);
    int lane = threadIdx.x & 63, wv = threadIdx.x >> 6;
    if (lane == 0) red8[wv] = v;
    __syncthreads();
    float s = 0.f;
#pragma unroll
    for (int i = 0; i < 8; ++i) s += red8[i];
    return s;
}

__device__ __forceinline__ float blockReduceMax512(float v) {  // 512 threads
    __shared__ float redm8[8];
    __syncthreads();
#pragma unroll
    for (int o = 32; o > 0; o >>= 1) v = fmaxf(v, __shfl_down(v, o, 64));
    int lane = threadIdx.x & 63, wv = threadIdx.x >> 6;
    if (lane == 0) redm8[wv] = v;
    __syncthreads();
    float m = redm8[0];
#pragma unroll
    for (int i = 1; i < 8; ++i) m = fmaxf(m, redm8[i]);
    return m;
}

// ============ merged prep: 3x weight-transpose + std stats ============
// K=32 frag-major layout: [k][cb][tap] blocks of 4096 ush, inner [n][g8][l16][e8].
__global__ __launch_bounds__(TPB) void prep_k(
    const float* __restrict__ w2, const float* __restrict__ w3,
    const float* __restrict__ w4, const float* __restrict__ x,
    ushort* __restrict__ wt2, ushort* __restrict__ wt3,
    ushort* __restrict__ wt4, float* __restrict__ st) {
    const int bid = blockIdx.x;
    if (bid < 9216) {
        __shared__ float ld[1152];
        const float* w = bid < 3072 ? w2 : (bid < 6144 ? w3 : w4);
        ushort* wt = bid < 3072 ? wt2 : (bid < 6144 ? wt3 : wt4);
        const int kk = (bid % 3072) >> 7, cout = bid & 127;
        const float* src = w + (size_t)(kk * 128 + cout) * 1152;
        for (int i = threadIdx.x; i < 1152; i += TPB) ld[i] = src[i];
        __syncthreads();
        const int n = cout >> 4, l16 = cout & 15;
        for (int e = threadIdx.x; e < 1152; e += TPB) {
            int cb = e / 288, r = e - cb * 288, tap = r >> 5, c32 = r & 31;
            int cin = cb * 32 + c32;
            size_t d = (size_t)((kk * 4 + cb) * 9 + tap) * 4096
                     + n * 512 + (c32 >> 3) * 128 + l16 * 8 + (c32 & 7);
            wt[d] = f2b(ld[cin * 9 + tap]);
        }
    } else {
        const int b = bid - 9216;
        const float* xb = x + b * 1600;
        float s = 0.f, s2 = 0.f;
        for (int p = threadIdx.x; p < 1600; p += TPB) {
            float v = xb[p];
            s += v; s2 += v * v;
        }
        s = blockReduceSum(s);
        s2 = blockReduceSum(s2);
        if (threadIdx.x == 0) {
            float mean = s / 1600.f;
            float var = (s2 - 1600.f * mean * mean) / 1599.f;
            float sd = sqrtf(var);
            st[b * 2] = rsqrtf(sd * 6.283185307179586f);   // mult
            st[b * 2 + 1] = -1.f / (2.f * sd * sd);        // pw
        }
    }
}

// ============ MEGA-KERNEL (512 thr): wave-specialized phase A ============
// Phase A: waves 0-3 = conv2 MFMA consumers (read As[cb&1]); waves 4-7 = conv1
// VALU producers (write As[(cb+1)&1]). ONE barrier per cb; VALU/MFMA overlap by
// construction (each SIMD hosts one wave of each role). As double-buffered.
// Phases B/C: all 8 waves (2 frags/wave). Phases D/E: 512-thread forms.
// LDS pool: phase A = xs(6400B)+As0+As1(2x28880) = 64160B; later phases reuse.
__global__ __launch_bounds__(512) void convall_k(
    const float* __restrict__ x, const float* __restrict__ w1,
    const float* __restrict__ b1,
    const ushort* __restrict__ wt2, const float* __restrict__ b2,
    const ushort* __restrict__ wt3, const float* __restrict__ b3,
    const ushort* __restrict__ wt4, const float* __restrict__ b4,
    const float* __restrict__ w5, const float* __restrict__ b5,
    const float* __restrict__ tpl,
    float* __restrict__ dmv, float* __restrict__ tt,
    float* __restrict__ mxs, float* __restrict__ out) {
    __shared__ __align__(16) ushort pool[32080];
    float*  xs  = (float*)pool;                  // 1600 f32
    ushort* As0 = pool + 3200;                   // 361*40 ush
    ushort* As1 = pool + 17640;                  // 361*40 ush
    ushort* h2L = pool;                          // 81*136 ush
    ushort* h3L = pool + 11016;                  // 49*136 ush
    float*  h4s = (float*)pool;                  // 128*25 f32
    float*  outs= (float*)(pool + 6400);
    float*  atts= (float*)(pool + 7200);
    float*  pooled = (float*)(pool + 7264);
    float*  tp  = (float*)(pool + 7400);

    const int bi = blockIdx.x;
    const int xcd = bi & 7, jj = bi >> 3;
    const int k = xcd * 3 + jj % 3, b = jj / 3;  // k-clustered per XCD
    const int bkL = b * 24 + k;
    const int tid = threadIdx.x;
    const int w = tid >> 6, l = tid & 63, l16 = l & 15, g = l >> 4;

    // ======== phase A: specialized conv1(producers) + conv2(consumers) ========
    {
        constexpr int OP = 81, STR = 40;
        const int mgrp = (w >> 1) & 1, ngrp = w & 1;     // consumer partition (w<4)
        const int tid2 = tid & 255;                      // producer threads
        const int sl = tid2 & 7, p0 = tid2 >> 3;
        const ushort* wb = wt2 + (size_t)k * 36 * 4096 + ngrp * 2048 + g * 128 + l16 * 8;
        const float* w1k = w1 + (size_t)k * 1152;
        const float* b1k = b1 + k * 128;

        for (int i = tid; i < 400; i += 512)
            ((f32x4*)xs)[i] = ((const f32x4*)(x + b * 1600))[i];

        f32x4 acc[3][4];
#pragma unroll
        for (int m = 0; m < 3; ++m)
#pragma unroll
            for (int n = 0; n < 4; ++n) acc[m][n] = (f32x4)0.f;

        int ibase[3];
#pragma unroll
        for (int m = 0; m < 3; ++m) {
            int row = (mgrp * 3 + m) * 16 + l16;
            row = row < OP ? row : OP - 1;
            int oy = row / 9, ox = row - oy * 9;
            ibase[m] = oy * 38 + ox * 2;
        }

        // conv1 slab writer (producer waves): 256 threads, runtime cb
        auto conv1_slab = [&](int cb, ushort* dA) {
            float wq[36], bq[4];
            const float* wsrc = w1k + (cb * 32 + sl * 4) * 9;
#pragma unroll
            for (int i2 = 0; i2 < 9; ++i2) ((f32x4*)wq)[i2] = ((const f32x4*)wsrc)[i2];
            *(f32x4*)bq = *(const f32x4*)(b1k + cb * 32 + sl * 4);
            for (int p = p0; p < 361; p += 32) {
                int py = p / 19, px = p - py * 19;
                const float* xb = xs + py * 80 + px * 2;
                float xt[9];
#pragma unroll
                for (int dy = 0; dy < 3; ++dy)
#pragma unroll
                    for (int dx = 0; dx < 3; ++dx) xt[dy * 3 + dx] = xb[dy * 40 + dx];
                s16x4 v;
#pragma unroll
                for (int j2 = 0; j2 < 4; ++j2) {
                    float s2 = bq[j2];
#pragma unroll
                    for (int t9 = 0; t9 < 9; ++t9) s2 += wq[j2 * 9 + t9] * xt[t9];
                    v[j2] = (short)f2b(fmaxf(s2, 0.f));
                }
                *(s16x4*)(dA + p * STR + 8 * ((sl >> 1) ^ ((p >> 3) & 1)) + (sl & 1) * 4) = v;
            }
        };

        s16x8 breg[3][4];
        __syncthreads();                         // xs visible
        if (w >= 4) {
            conv1_slab(0, As0);
        } else {
#pragma unroll
            for (int n = 0; n < 4; ++n) breg[0][n] = *(const s16x8*)(wb + n * 512);
#pragma unroll
            for (int n = 0; n < 4; ++n) breg[1][n] = *(const s16x8*)(wb + 4096 + n * 512);
        }
        __syncthreads();                         // As0 ready

#pragma unroll 1
        for (int cb = 0; cb < 4; ++cb) {
            ushort* curA = (cb & 1) ? As1 : As0;
            ushort* nxtA = (cb & 1) ? As0 : As1;
            if (w >= 4) {
                if (cb < 3) conv1_slab(cb + 1, nxtA);
            } else {
#pragma unroll
                for (int tap = 0; tap < 9; ++tap) {
                    const int it = cb * 9 + tap;        // buffer idx tap%3 static
                    if (it + 2 < 36) {                  // 3-deep ring, distance 2
                        const ushort* src = wb + (size_t)(it + 2) * 4096;
#pragma unroll
                        for (int n = 0; n < 4; ++n)
                            breg[(tap + 2) % 3][n] = *(const s16x8*)(src + n * 512);
                    }
                    const int ioff = (tap / 3) * 19 + (tap % 3);
                    s16x8 a[3];
#pragma unroll
                    for (int m = 0; m < 3; ++m) {
                        int ip = ibase[m] + ioff;
                        a[m] = *(const s16x8*)(curA + ip * STR + 8 * (g ^ ((ip >> 3) & 1)));
                    }
#pragma unroll
                    for (int n = 0; n < 4; ++n)
#pragma unroll
                        for (int m = 0; m < 3; ++m)
                            acc[m][n] = __builtin_amdgcn_mfma_f32_16x16x32_bf16(a[m], breg[tap % 3][n], acc[m][n], 0, 0, 0);
                }
            }
            __syncthreads();                     // As[(cb+1)&1] complete; reads done
        }
        // epilogue (consumer waves hold acc) -> h2L (overlaps xs/As0; all reads done)
        if (w < 4) {
#pragma unroll
            for (int n = 0; n < 4; ++n) {
                int cout = (ngrp * 4 + n) * 16 + l16;
                float bv = b2[k * 128 + cout];
#pragma unroll
                for (int m = 0; m < 3; ++m)
#pragma unroll
                    for (int r = 0; r < 4; ++r) {
                        int row = (mgrp * 3 + m) * 16 + g * 4 + r;
                        if (row < OP)
                            h2L[row * 136 + cout] = f2b(fmaxf(acc[m][n][r] + bv, 0.f));
                    }
            }
        }
    }
    __syncthreads();                             // h2L visible

    // ======== phase B: conv3 (9x9 -> 7x7), 8 waves, h2L -> h3L ========
    {
        constexpr int OP = 49;
        const int mg = w >> 2, ng = w & 3;
        const ushort* wb = wt3 + (size_t)k * 36 * 4096 + ng * 1024 + g * 128 + l16 * 8;
        s16x8 breg[3][2];
#pragma unroll
        for (int n = 0; n < 2; ++n) breg[0][n] = *(const s16x8*)(wb + n * 512);
#pragma unroll
        for (int n = 0; n < 2; ++n) breg[1][n] = *(const s16x8*)(wb + 4096 + n * 512);

        f32x4 acc[2][2];
#pragma unroll
        for (int m = 0; m < 2; ++m)
#pragma unroll
            for (int n = 0; n < 2; ++n) acc[m][n] = (f32x4)0.f;

        int ibase[2];
#pragma unroll
        for (int m = 0; m < 2; ++m) {
            int row = (mg * 2 + m) * 16 + l16;
            row = row < OP ? row : OP - 1;
            int oy = row / 7, ox = row - oy * 7;
            ibase[m] = oy * 9 + ox;
        }
#pragma unroll 1
        for (int cb = 0; cb < 4; ++cb)
#pragma unroll
            for (int tap = 0; tap < 9; ++tap) {
                const int it = cb * 9 + tap;
                if (it + 2 < 36) {
                    const ushort* src = wb + (size_t)(it + 2) * 4096;
#pragma unroll
                    for (int n = 0; n < 2; ++n)
                        breg[(tap + 2) % 3][n] = *(const s16x8*)(src + n * 512);
                }
                const int ioff = (tap / 3) * 9 + (tap % 3);
                s16x8 a[2];
#pragma unroll
                for (int m = 0; m < 2; ++m)
                    a[m] = *(const s16x8*)(h2L + (ibase[m] + ioff) * 136 + cb * 32 + g * 8);
#pragma unroll
                for (int n = 0; n < 2; ++n)
#pragma unroll
                    for (int m = 0; m < 2; ++m)
                        acc[m][n] = __builtin_amdgcn_mfma_f32_16x16x32_bf16(a[m], breg[tap % 3][n], acc[m][n], 0, 0, 0);
            }
        // epilogue -> h3L (disjoint from h2L)
#pragma unroll
        for (int n = 0; n < 2; ++n) {
            int cout = (ng * 2 + n) * 16 + l16;
            float bv = b3[k * 128 + cout];
#pragma unroll
            for (int m = 0; m < 2; ++m)
#pragma unroll
                for (int r = 0; r < 4; ++r) {
                    int row = (mg * 2 + m) * 16 + g * 4 + r;
                    if (row < OP)
                        h3L[row * 136 + cout] = f2b(fmaxf(acc[m][n][r] + bv, 0.f));
                }
        }
    }
    __syncthreads();                             // h3L visible (h2L dead)

    // ======== phase C: conv4 (7x7 -> 5x5), 8 waves, h3L -> h4s (f32) ========
    {
        constexpr int OP = 25;
        const int mg = w >> 2, ng = w & 3;
        const ushort* wb = wt4 + (size_t)k * 36 * 4096 + ng * 1024 + g * 128 + l16 * 8;
        s16x8 breg[3][2];
#pragma unroll
        for (int n = 0; n < 2; ++n) breg[0][n] = *(const s16x8*)(wb + n * 512);
#pragma unroll
        for (int n = 0; n < 2; ++n) breg[1][n] = *(const s16x8*)(wb + 4096 + n * 512);

        f32x4 acc[2];
#pragma unroll
        for (int n = 0; n < 2; ++n) acc[n] = (f32x4)0.f;

        int ibase;
        {
            int row = mg * 16 + l16;
            row = row < OP ? row : OP - 1;
            int oy = row / 5, ox = row - oy * 5;
            ibase = oy * 7 + ox;
        }
#pragma unroll 1
        for (int cb = 0; cb < 4; ++cb)
#pragma unroll
            for (int tap = 0; tap < 9; ++tap) {
                const int it = cb * 9 + tap;
                if (it + 2 < 36) {
                    const ushort* src = wb + (size_t)(it + 2) * 4096;
#pragma unroll
                    for (int n = 0; n < 2; ++n)
                        breg[(tap + 2) % 3][n] = *(const s16x8*)(src + n * 512);
                }
                const int ioff = (tap / 3) * 7 + (tap % 3);
                s16x8 a = *(const s16x8*)(h3L + (ibase + ioff) * 136 + cb * 32 + g * 8);
#pragma unroll
                for (int n = 0; n < 2; ++n)
                    acc[n] = __builtin_amdgcn_mfma_f32_16x16x32_bf16(a, breg[tap % 3][n], acc[n], 0, 0, 0);
            }
        // epilogue -> h4s[cout*25 + row] f32 (disjoint from h3L)
#pragma unroll
        for (int n = 0; n < 2; ++n) {
            int cout = (ng * 2 + n) * 16 + l16;
            float bv = b4[k * 128 + cout];
#pragma unroll
            for (int r = 0; r < 4; ++r) {
                int row = mg * 16 + g * 4 + r;
                if (row < OP)
                    h4s[cout * 25 + row] = fmaxf(acc[n][r] + bv, 0.f);
            }
        }
    }
    __syncthreads();                             // h4s visible

    // ======== phase D: conv5 (1x1) + attention + pooling + heads ========
    for (int t = tid; t < 400; t += 512) {
        int f = t / 25, pix = t - f * 25;
        const float* wp = w5 + (size_t)(k * 16 + f) * 128;
        float s = b5[k * 16 + f];
        for (int c = 0; c < 128; ++c) s += wp[c] * h4s[c * 25 + pix];
        outs[t] = s;
    }
    __syncthreads();
    if (tid < 25) {
        int y5 = tid / 5;
        const float* row = outs + 15 * 25 + y5 * 5;
        float mx = row[0];
#pragma unroll
        for (int j = 1; j < 5; ++j) mx = fmaxf(mx, row[j]);
        float ssum = 0.f;
#pragma unroll
        for (int j = 0; j < 5; ++j) ssum += expf(row[j] - mx);
        atts[tid] = expf(outs[15 * 25 + tid] - mx) / ssum;
    }
    __syncthreads();
    if (tid < 15) {
        float s = 0.f;
        const float* row = outs + tid * 25;
#pragma unroll
        for (int p = 0; p < 25; ++p) s += row[p] * atts[p];
        pooled[tid] = s;
    }
    __syncthreads();                             // pooled visible to all
    float* oc = out + OUT_OC + (size_t)bkL * 136;
    if (tid < 6) {
        float v = fmaxf(pooled[tid], 0.f);
        oc[1 + tid] = v;
        out[OUT_XM + bkL * 6 + tid] = v;
    } else if (tid == 6) {
        float d = 1.f / (1.f + expf(-pooled[6]));
        dmv[bkL] = d;
        oc[0] = d;
        out[OUT_DM + bkL] = d;
    } else if (tid >= 7 && tid < 15) {
        oc[128 + tid - 7] = fmaxf(pooled[tid], 0.f);
    }
    for (int t = tid; t < 121; t += 512) oc[7 + t] = tpl[k * 121 + t];

    // ======== phase E: affine warp + bilinear TS->40x40 + mix softmax stats ========
    for (int i = tid; i < 121; i += 512) tp[i] = tpl[k * 121 + i];
    {
        const float D2R = 0.017453292519943295f;
        float ang = fmaxf(pooled[0], 0.f) * D2R;
        float txp = fmaxf(pooled[1], 0.f), typ = fmaxf(pooled[2], 0.f);
        float sc  = fmaxf(fmaxf(pooled[3], 0.f), 1e-2f);
        float shx = fmaxf(pooled[4], 0.f) * D2R;
        float shy = fmaxf(pooled[5], 0.f) * D2R;
        float dm  = 1.f / (1.f + expf(-pooled[6]));
        float cams = cosf(ang - shy), sams = sinf(ang - shy);
        float cshy = cosf(shy), tshx = tanf(shx);
        float av = cams / cshy;
        float bv = -cams * tshx / cshy - sinf(ang);
        float cv = sams / cshy;
        float dv = -sams * tshx / cshy + cosf(ang);
        float m0 = dv / sc, m1 = -bv / sc, m3 = -cv / sc, m4 = av / sc;
        float m2 = m0 * (-5.f - txp) + m1 * (-5.f - typ) + 5.f;
        float m5 = m3 * (-5.f - txp) + m4 * (-5.f - typ) + 5.f;
        __syncthreads();                         // tp visible
        float* to = tt + (size_t)bkL * 1600;
        float tvl[4];
#pragma unroll
        for (int r = 0; r < 4; ++r) {
            int p = tid + r * 512;
            float val = 0.f;
            if (p < 1600) {
                int i = p / 40, jx = p - (p / 40) * 40;
                float gx = (jx + 0.5f) * (11.f / 40.f) - 0.5f;
                float gy = (i + 0.5f) * (11.f / 40.f) - 0.5f;
                float xin = m0 * gx + m1 * gy + m2;
                float yin = m3 * gx + m4 * gy + m5;
                float x0 = floorf(xin), y0 = floorf(yin);
                float wx = xin - x0, wy = yin - y0;
                int x0i = (int)x0, y0i = (int)y0;
                auto tapf = [&](int yy, int xx) -> float {
                    bool valid = (xx >= 0) && (xx < TSz) && (yy >= 0) && (yy < TSz);
                    int yc = min(max(yy, 0), TSz - 1), xc = min(max(xx, 0), TSz - 1);
                    float v = tp[yc * TSz + xc];
                    return valid ? v : 0.f;
                };
                float v00 = tapf(y0i, x0i),     v01 = tapf(y0i, x0i + 1);
                float v10 = tapf(y0i + 1, x0i), v11 = tapf(y0i + 1, x0i + 1);
                val = v00 * (1.f - wx) * (1.f - wy) + v01 * wx * (1.f - wy) +
                      v10 * (1.f - wx) * wy + v11 * wx * wy;
                to[p] = val;
            }
            tvl[r] = val;
        }
        float mx = -1e30f;
#pragma unroll
        for (int r = 0; r < 4; ++r) {
            int p = tid + r * 512;
            if (p < 1600) mx = fmaxf(mx, dm * tvl[r]);
        }
        mx = blockReduceMax512(mx);
        float s = 0.f;
#pragma unroll
        for (int r = 0; r < 4; ++r) {
            int p = tid + r * 512;
            if (p < 1600) s += expf(dm * tvl[r] - mx);
        }
        s = blockReduceSum512(s);
        if (tid == 0) { mxs[bkL * 2] = mx; mxs[bkL * 2 + 1] = s; }
    }
}

// ============ log-likelihood, split over 8 pixel-blocks per sample ============
__global__ __launch_bounds__(TPB) void ll_k(const float* __restrict__ x,
                                            const float* __restrict__ tt,
                                            const float* __restrict__ dmv,
                                            const float* __restrict__ mxs,
                                            const float* __restrict__ st,
                                            float* __restrict__ part) {
    const int b = blockIdx.x, sp = blockIdx.y;
    __shared__ float dms[24], mxh[24], sih[24];
    if (threadIdx.x < 24) {
        int bk = b * 24 + threadIdx.x;
        dms[threadIdx.x] = dmv[bk];
        mxh[threadIdx.x] = mxs[bk * 2];
        sih[threadIdx.x] = 1.f / mxs[bk * 2 + 1];
    }
    __syncthreads();
    const float mult = st[b * 2], pw = st[b * 2 + 1];
    const float* xb = x + b * 1600;
    const float* tb = tt + (size_t)b * 24 * 1600;
    float acc = 0.f;
    int p = sp * 200 + threadIdx.x;
    if (threadIdx.x < 200) {
        float xv = xb[p];
        float ssum = 0.f;
        for (int k = 0; k < 24; ++k) {
            float tv = tb[(size_t)k * 1600 + p];
            float dd = xv - tv;
            float g = mult * expf(dd * dd * pw);
            float mixv = expf(dms[k] * tv - mxh[k]) * sih[k];
            ssum += g * mixv;
        }
        acc = logf(ssum);
    }
    acc = blockReduceSum(acc);
    if (threadIdx.x == 0) part[b * 8 + sp] = acc;
}

__global__ void fin_k(const float* __restrict__ part, float* __restrict__ out) {
    float v = 0.f;
#pragma unroll
    for (int q = 0; q < 8; ++q) v += part[threadIdx.x * 8 + q];
#pragma unroll
    for (int o = 32; o > 0; o >>= 1) v += __shfl_down(v, o, 64);
    if (threadIdx.x == 0) out[0] = v * (1.f / 64.f);
}

// ============ launch ============
extern "C" void kernel_launch(void* const* d_in, const int* in_sizes, int n_in,
                              void* d_out, int out_size, void* d_ws, size_t ws_size,
                              hipStream_t stream) {
    const float* x   = (const float*)d_in[0];
    const float* w1  = (const float*)d_in[1];
    const float* b1  = (const float*)d_in[2];
    const float* w2  = (const float*)d_in[3];
    const float* b2  = (const float*)d_in[4];
    const float* w3  = (const float*)d_in[5];
    const float* b3  = (const float*)d_in[6];
    const float* w4  = (const float*)d_in[7];
    const float* b4  = (const float*)d_in[8];
    const float* w5  = (const float*)d_in[9];
    const float* b5  = (const float*)d_in[10];
    const float* tpl = (const float*)d_in[11];
    float* out = (float*)d_out;
    char* W = (char*)d_ws;

    ushort* wt2 = (ushort*)(W + OFFB_W2);
    ushort* wt3 = (ushort*)(W + OFFB_W3);
    ushort* wt4 = (ushort*)(W + OFFB_W4);
    float*  dmv  = (float*)(W + OFFB_DMV);
    float*  ttb  = (float*)(W + OFFB_TT);
    float*  stv  = (float*)(W + OFFB_ST);
    float*  mxs  = (float*)(W + OFFB_MXS);
    float*  part = (float*)(W + OFFB_PART);

    prep_k<<<3 * 3072 + Bn, TPB, 0, stream>>>(w2, w3, w4, x, wt2, wt3, wt4, stv);
    convall_k<<<NBK, 512, 0, stream>>>(x, w1, b1, wt2, b2, wt3, b3, wt4, b4,
                                       w5, b5, tpl, dmv, ttb, mxs, out);
    ll_k<<<dim3(Bn, 8), TPB, 0, stream>>>(x, ttb, dmv, mxs, stv, part);
    fin_k<<<1, 64, 0, stream>>>(part, out);
}

// Round 16
// 197.589 us; speedup vs baseline: 1.2023x; 1.2023x over previous
//
#include <hip/hip_runtime.h>
#include <math.h>

#define TPB 256

typedef __attribute__((ext_vector_type(8))) short s16x8;
typedef __attribute__((ext_vector_type(4))) short s16x4;
typedef __attribute__((ext_vector_type(4))) float f32x4;
typedef unsigned int u32;

constexpr int Bn = 64, Kc = 24, TSz = 11;
constexpr int NBK = Bn * Kc;          // 1536

// ---- workspace offsets (BYTES) ----
constexpr size_t SZW_B    = (size_t)Kc * 36 * 4096 * 2;      // 7,077,888 B/plane
constexpr size_t OFFB_W2  = 0;
constexpr size_t OFFB_W3  = OFFB_W2 + SZW_B;
constexpr size_t OFFB_W4  = OFFB_W3 + SZW_B;
constexpr size_t OFFB_DMV = OFFB_W4 + SZW_B;
constexpr size_t OFFB_TT  = OFFB_DMV + (size_t)NBK * 4;
constexpr size_t OFFB_ST  = OFFB_TT + (size_t)NBK * 1600 * 4;
constexpr size_t OFFB_MXS = OFFB_ST + 512;
constexpr size_t OFFB_PART= OFFB_MXS + (size_t)NBK * 2 * 4;

// ---- output offsets (floats) ----
constexpr int OUT_OC = 1;                   // input_ocae [B,K,136]
constexpr int OUT_XM = 1 + NBK * 136;
constexpr int OUT_DM = OUT_XM + NBK * 6;

// ============ bf16 helpers ============
__device__ __forceinline__ ushort f2b(float f) {
    union { float f; unsigned u; } c; c.f = f;
    unsigned r = c.u + 0x7fffu + ((c.u >> 16) & 1u);
    return (ushort)(r >> 16);
}
__device__ __forceinline__ float b2f(ushort h) {
    union { unsigned u; float f; } c; c.u = ((unsigned)h) << 16; return c.f;
}

// ============ reductions (256 threads → 4 waves) ============
__device__ __forceinline__ float blockReduceSum(float v) {
    __shared__ float red[4];
    __syncthreads();
#pragma unroll
    for (int o = 32; o > 0; o >>= 1) v += __shfl_down(v, o, 64);
    int lane = threadIdx.x & 63, wv = threadIdx.x >> 6;
    if (lane == 0) red[wv] = v;
    __syncthreads();
    return red[0] + red[1] + red[2] + red[3];
}

__device__ __forceinline__ float blockReduceMax(float v) {
    __shared__ float redm[4];
    __syncthreads();
#pragma unroll
    for (int o = 32; o > 0; o >>= 1) v = fmaxf(v, __shfl_down(v, o, 64));
    int lane = threadIdx.x & 63, wv = threadIdx.x >> 6;
    if (lane == 0) redm[wv] = v;
    __syncthreads();
    return fmaxf(fmaxf(redm[0], redm[1]), fmaxf(redm[2], redm[3]));
}

// ============ merged prep: 3x weight-transpose + std stats ============
// K=32 frag-major layout: [k][cb][tap] blocks of 4096 ush, inner [n][g8][l16][e8].
__global__ __launch_bounds__(TPB) void prep_k(
    const float* __restrict__ w2, const float* __restrict__ w3,
    const float* __restrict__ w4, const float* __restrict__ x,
    ushort* __restrict__ wt2, ushort* __restrict__ wt3,
    ushort* __restrict__ wt4, float* __restrict__ st) {
    const int bid = blockIdx.x;
    if (bid < 9216) {
        __shared__ float ld[1152];
        const float* w = bid < 3072 ? w2 : (bid < 6144 ? w3 : w4);
        ushort* wt = bid < 3072 ? wt2 : (bid < 6144 ? wt3 : wt4);
        const int kk = (bid % 3072) >> 7, cout = bid & 127;
        const float* src = w + (size_t)(kk * 128 + cout) * 1152;
        for (int i = threadIdx.x; i < 1152; i += TPB) ld[i] = src[i];
        __syncthreads();
        const int n = cout >> 4, l16 = cout & 15;
        for (int e = threadIdx.x; e < 1152; e += TPB) {
            int cb = e / 288, r = e - cb * 288, tap = r >> 5, c32 = r & 31;
            int cin = cb * 32 + c32;
            size_t d = (size_t)((kk * 4 + cb) * 9 + tap) * 4096
                     + n * 512 + (c32 >> 3) * 128 + l16 * 8 + (c32 & 7);
            wt[d] = f2b(ld[cin * 9 + tap]);
        }
    } else {
        const int b = bid - 9216;
        const float* xb = x + b * 1600;
        float s = 0.f, s2 = 0.f;
        for (int p = threadIdx.x; p < 1600; p += TPB) {
            float v = xb[p];
            s += v; s2 += v * v;
        }
        s = blockReduceSum(s);
        s2 = blockReduceSum(s2);
        if (threadIdx.x == 0) {
            float mean = s / 1600.f;
            float var = (s2 - 1600.f * mean * mean) / 1599.f;
            float sd = sqrtf(var);
            st[b * 2] = rsqrtf(sd * 6.283185307179586f);   // mult
            st[b * 2 + 1] = -1.f / (2.f * sd * sd);        // pw
        }
    }
}

// ============ MEGA-KERNEL: conv1..conv4->head->warp, I$-compact ============
// Round-14 proven structure (best: 197us). cb loops are RUNTIME loops
// (#pragma unroll 1) so code fits the 32KB I$. B rings 3-deep: buffer index
// (9*cb+tap)%3 == tap%3 -> compile-time static per tap (rule #20 safe).
__global__ __launch_bounds__(256) void convall_k(
    const float* __restrict__ x, const float* __restrict__ w1,
    const float* __restrict__ b1,
    const ushort* __restrict__ wt2, const float* __restrict__ b2,
    const ushort* __restrict__ wt3, const float* __restrict__ b3,
    const ushort* __restrict__ wt4, const float* __restrict__ b4,
    const float* __restrict__ w5, const float* __restrict__ b5,
    const float* __restrict__ tpl,
    float* __restrict__ dmv, float* __restrict__ tt,
    float* __restrict__ mxs, float* __restrict__ out) {
    __shared__ __align__(16) ushort pool[17680];
    float*  xs  = (float*)pool;
    ushort* As  = pool + 3200;
    ushort* h2L = pool;
    ushort* h3L = pool + 11016;
    float*  h4s = (float*)pool;
    float*  outs= (float*)(pool + 6400);
    float*  atts= (float*)(pool + 7200);
    float*  pooled = (float*)(pool + 7264);
    float*  tp  = (float*)(pool + 7400);

    const int bi = blockIdx.x;
    const int xcd = bi & 7, jj = bi >> 3;
    const int k = xcd * 3 + jj % 3, b = jj / 3;  // k-clustered per XCD
    const int bkL = b * 24 + k;
    const int tid = threadIdx.x;
    const int w = tid >> 6, l = tid & 63, l16 = l & 15, g = l >> 4;
    const int mgrp = w >> 1, ngrp = w & 1;

    // ======== phase A: fused conv1+conv2 ========
    {
        constexpr int OP = 81, STR = 40;
        const int sl = tid & 7, p0 = tid >> 3;
        const ushort* wb = wt2 + (size_t)k * 36 * 4096 + ngrp * 2048 + g * 128 + l16 * 8;
        const float* w1k = w1 + (size_t)k * 1152;
        const float* b1k = b1 + k * 128;

        for (int i = tid; i < 400; i += 256)
            ((f32x4*)xs)[i] = ((const f32x4*)(x + b * 1600))[i];

        f32x4 acc[3][4];
#pragma unroll
        for (int m = 0; m < 3; ++m)
#pragma unroll
            for (int n = 0; n < 4; ++n) acc[m][n] = (f32x4)0.f;

        int ibase[3];
#pragma unroll
        for (int m = 0; m < 3; ++m) {
            int row = (mgrp * 3 + m) * 16 + l16;
            row = row < OP ? row : OP - 1;
            int oy = row / 9, ox = row - oy * 9;
            ibase[m] = oy * 38 + ox * 2;
        }

        // conv1 slab writer (runtime cb): weights loaded here
        auto conv1_slab = [&](int cb) {
            float wq[36], bq[4];
            const float* wsrc = w1k + (cb * 32 + sl * 4) * 9;
#pragma unroll
            for (int i2 = 0; i2 < 9; ++i2) ((f32x4*)wq)[i2] = ((const f32x4*)wsrc)[i2];
            *(f32x4*)bq = *(const f32x4*)(b1k + cb * 32 + sl * 4);
            for (int p = p0; p < 361; p += 32) {
                int py = p / 19, px = p - py * 19;
                const float* xb = xs + py * 80 + px * 2;
                float xt[9];
#pragma unroll
                for (int dy = 0; dy < 3; ++dy)
#pragma unroll
                    for (int dx = 0; dx < 3; ++dx) xt[dy * 3 + dx] = xb[dy * 40 + dx];
                s16x4 v;
#pragma unroll
                for (int j2 = 0; j2 < 4; ++j2) {
                    float s2 = bq[j2];
#pragma unroll
                    for (int t9 = 0; t9 < 9; ++t9) s2 += wq[j2 * 9 + t9] * xt[t9];
                    v[j2] = (short)f2b(fmaxf(s2, 0.f));
                }
                *(s16x4*)(As + p * STR + 8 * ((sl >> 1) ^ ((p >> 3) & 1)) + (sl & 1) * 4) = v;
            }
        };

        s16x8 breg[3][4];
        __syncthreads();                         // xs visible
        conv1_slab(0);
#pragma unroll
        for (int n = 0; n < 4; ++n) breg[0][n] = *(const s16x8*)(wb + n * 512);
#pragma unroll
        for (int n = 0; n < 4; ++n) breg[1][n] = *(const s16x8*)(wb + 4096 + n * 512);
        __syncthreads();                         // As ready

#pragma unroll 1
        for (int cb = 0; cb < 4; ++cb) {
#pragma unroll
            for (int tap = 0; tap < 9; ++tap) {
                const int it = cb * 9 + tap;     // runtime; buffer idx tap%3 static
                if (it + 2 < 36) {               // 3-deep ring, prefetch distance 2
                    const ushort* src = wb + (size_t)(it + 2) * 4096;
#pragma unroll
                    for (int n = 0; n < 4; ++n)
                        breg[(tap + 2) % 3][n] = *(const s16x8*)(src + n * 512);
                }
                const int ioff = (tap / 3) * 19 + (tap % 3);
                s16x8 a[3];
#pragma unroll
                for (int m = 0; m < 3; ++m) {
                    int ip = ibase[m] + ioff;
                    a[m] = *(const s16x8*)(As + ip * STR + 8 * (g ^ ((ip >> 3) & 1)));
                }
#pragma unroll
                for (int n = 0; n < 4; ++n)
#pragma unroll
                    for (int m = 0; m < 3; ++m)
                        acc[m][n] = __builtin_amdgcn_mfma_f32_16x16x32_bf16(a[m], breg[tap % 3][n], acc[m][n], 0, 0, 0);
            }
            if (cb < 3) {
                __syncthreads();
                conv1_slab(cb + 1);
                __syncthreads();
            }
        }
        __syncthreads();                         // all As reads done before h2L overwrite
        // epilogue -> h2L (LDS, stride 136)
#pragma unroll
        for (int n = 0; n < 4; ++n) {
            int cout = (ngrp * 4 + n) * 16 + l16;
            float bv = b2[k * 128 + cout];
#pragma unroll
            for (int m = 0; m < 3; ++m)
#pragma unroll
                for (int r = 0; r < 4; ++r) {
                    int row = (mgrp * 3 + m) * 16 + g * 4 + r;
                    if (row < OP)
                        h2L[row * 136 + cout] = f2b(fmaxf(acc[m][n][r] + bv, 0.f));
                }
        }
    }
    __syncthreads();                             // h2L visible

    // ======== phase B: conv3 (9x9 -> 7x7), h2L -> h3L ========
    {
        constexpr int OP = 49;
        const ushort* wb = wt3 + (size_t)k * 36 * 4096 + ngrp * 2048 + g * 128 + l16 * 8;
        s16x8 breg[3][4];
#pragma unroll
        for (int n = 0; n < 4; ++n) breg[0][n] = *(const s16x8*)(wb + n * 512);
#pragma unroll
        for (int n = 0; n < 4; ++n) breg[1][n] = *(const s16x8*)(wb + 4096 + n * 512);

        f32x4 acc[2][4];
#pragma unroll
        for (int m = 0; m < 2; ++m)
#pragma unroll
            for (int n = 0; n < 4; ++n) acc[m][n] = (f32x4)0.f;

        int ibase[2];
#pragma unroll
        for (int m = 0; m < 2; ++m) {
            int row = (mgrp * 2 + m) * 16 + l16;
            row = row < OP ? row : OP - 1;
            int oy = row / 7, ox = row - oy * 7;
            ibase[m] = oy * 9 + ox;
        }
#pragma unroll 1
        for (int cb = 0; cb < 4; ++cb)
#pragma unroll
            for (int tap = 0; tap < 9; ++tap) {
                const int it = cb * 9 + tap;
                if (it + 2 < 36) {
                    const ushort* src = wb + (size_t)(it + 2) * 4096;
#pragma unroll
                    for (int n = 0; n < 4; ++n)
                        breg[(tap + 2) % 3][n] = *(const s16x8*)(src + n * 512);
                }
                const int ioff = (tap / 3) * 9 + (tap % 3);
                s16x8 a[2];
#pragma unroll
                for (int m = 0; m < 2; ++m)
                    a[m] = *(const s16x8*)(h2L + (ibase[m] + ioff) * 136 + cb * 32 + g * 8);
#pragma unroll
                for (int n = 0; n < 4; ++n)
#pragma unroll
                    for (int m = 0; m < 2; ++m)
                        acc[m][n] = __builtin_amdgcn_mfma_f32_16x16x32_bf16(a[m], breg[tap % 3][n], acc[m][n], 0, 0, 0);
            }
        // epilogue -> h3L (disjoint from h2L)
#pragma unroll
        for (int n = 0; n < 4; ++n) {
            int cout = (ngrp * 4 + n) * 16 + l16;
            float bv = b3[k * 128 + cout];
#pragma unroll
            for (int m = 0; m < 2; ++m)
#pragma unroll
                for (int r = 0; r < 4; ++r) {
                    int row = (mgrp * 2 + m) * 16 + g * 4 + r;
                    if (row < OP)
                        h3L[row * 136 + cout] = f2b(fmaxf(acc[m][n][r] + bv, 0.f));
                }
        }
    }
    __syncthreads();                             // h3L visible (h2L dead)

    // ======== phase C: conv4 (7x7 -> 5x5), h3L -> h4s (f32, head layout) ========
    {
        constexpr int OP = 25;
        const ushort* wb = wt4 + (size_t)k * 36 * 4096 + ngrp * 2048 + g * 128 + l16 * 8;
        s16x8 breg[3][4];
#pragma unroll
        for (int n = 0; n < 4; ++n) breg[0][n] = *(const s16x8*)(wb + n * 512);
#pragma unroll
        for (int n = 0; n < 4; ++n) breg[1][n] = *(const s16x8*)(wb + 4096 + n * 512);

        f32x4 acc[4];
#pragma unroll
        for (int n = 0; n < 4; ++n) acc[n] = (f32x4)0.f;

        int ibase;
        {
            int row = mgrp * 16 + l16;
            row = row < OP ? row : OP - 1;
            int oy = row / 5, ox = row - oy * 5;
            ibase = oy * 7 + ox;
        }
#pragma unroll 1
        for (int cb = 0; cb < 4; ++cb)
#pragma unroll
            for (int tap = 0; tap < 9; ++tap) {
                const int it = cb * 9 + tap;
                if (it + 2 < 36) {
                    const ushort* src = wb + (size_t)(it + 2) * 4096;
#pragma unroll
                    for (int n = 0; n < 4; ++n)
                        breg[(tap + 2) % 3][n] = *(const s16x8*)(src + n * 512);
                }
                const int ioff = (tap / 3) * 7 + (tap % 3);
                s16x8 a = *(const s16x8*)(h3L + (ibase + ioff) * 136 + cb * 32 + g * 8);
#pragma unroll
                for (int n = 0; n < 4; ++n)
                    acc[n] = __builtin_amdgcn_mfma_f32_16x16x32_bf16(a, breg[tap % 3][n], acc[n], 0, 0, 0);
            }
        // epilogue -> h4s[cout*25 + row] f32 (disjoint from h3L)
#pragma unroll
        for (int n = 0; n < 4; ++n) {
            int cout = (ngrp * 4 + n) * 16 + l16;
            float bv = b4[k * 128 + cout];
#pragma unroll
            for (int r = 0; r < 4; ++r) {
                int row = mgrp * 16 + g * 4 + r;
                if (row < OP)
                    h4s[cout * 25 + row] = fmaxf(acc[n][r] + bv, 0.f);
            }
        }
    }
    __syncthreads();                             // h4s visible

    // ======== phase D: conv5 (1x1) + attention + pooling + heads ========
    for (int t = tid; t < 400; t += 256) {
        int f = t / 25, pix = t - f * 25;
        const float* wp = w5 + (size_t)(k * 16 + f) * 128;
        float s = b5[k * 16 + f];
        for (int c = 0; c < 128; ++c) s += wp[c] * h4s[c * 25 + pix];
        outs[t] = s;
    }
    __syncthreads();
    if (tid < 25) {
        int y5 = tid / 5;
        const float* row = outs + 15 * 25 + y5 * 5;
        float mx = row[0];
#pragma unroll
        for (int j = 1; j < 5; ++j) mx = fmaxf(mx, row[j]);
        float ssum = 0.f;
#pragma unroll
        for (int j = 0; j < 5; ++j) ssum += expf(row[j] - mx);
        atts[tid] = expf(outs[15 * 25 + tid] - mx) / ssum;
    }
    __syncthreads();
    if (tid < 15) {
        float s = 0.f;
        const float* row = outs + tid * 25;
#pragma unroll
        for (int p = 0; p < 25; ++p) s += row[p] * atts[p];
        pooled[tid] = s;
    }
    __syncthreads();                             // pooled visible to all
    float* oc = out + OUT_OC + (size_t)bkL * 136;
    if (tid < 6) {
        float v = fmaxf(pooled[tid], 0.f);
        oc[1 + tid] = v;
        out[OUT_XM + bkL * 6 + tid] = v;
    } else if (tid == 6) {
        float d = 1.f / (1.f + expf(-pooled[6]));
        dmv[bkL] = d;
        oc[0] = d;
        out[OUT_DM + bkL] = d;
    } else if (tid >= 7 && tid < 15) {
        oc[128 + tid - 7] = fmaxf(pooled[tid], 0.f);
    }
    for (int t = tid; t < 121; t += 256) oc[7 + t] = tpl[k * 121 + t];

    // ======== phase E: affine warp + bilinear TS->40x40 + mix softmax stats ========
    for (int i = tid; i < 121; i += 256) tp[i] = tpl[k * 121 + i];
    {
        const float D2R = 0.017453292519943295f;
        float ang = fmaxf(pooled[0], 0.f) * D2R;
        float txp = fmaxf(pooled[1], 0.f), typ = fmaxf(pooled[2], 0.f);
        float sc  = fmaxf(fmaxf(pooled[3], 0.f), 1e-2f);
        float shx = fmaxf(pooled[4], 0.f) * D2R;
        float shy = fmaxf(pooled[5], 0.f) * D2R;
        float dm  = 1.f / (1.f + expf(-pooled[6]));
        float cams = cosf(ang - shy), sams = sinf(ang - shy);
        float cshy = cosf(shy), tshx = tanf(shx);
        float av = cams / cshy;
        float bv = -cams * tshx / cshy - sinf(ang);
        float cv = sams / cshy;
        float dv = -sams * tshx / cshy + cosf(ang);
        float m0 = dv / sc, m1 = -bv / sc, m3 = -cv / sc, m4 = av / sc;
        float m2 = m0 * (-5.f - txp) + m1 * (-5.f - typ) + 5.f;
        float m5 = m3 * (-5.f - txp) + m4 * (-5.f - typ) + 5.f;
        __syncthreads();                         // tp visible
        float* to = tt + (size_t)bkL * 1600;
        float tvl[7];
#pragma unroll
        for (int r = 0; r < 7; ++r) {
            int p = tid + r * 256;
            float val = 0.f;
            if (p < 1600) {
                int i = p / 40, jx = p - (p / 40) * 40;
                float gx = (jx + 0.5f) * (11.f / 40.f) - 0.5f;
                float gy = (i + 0.5f) * (11.f / 40.f) - 0.5f;
                float xin = m0 * gx + m1 * gy + m2;
                float yin = m3 * gx + m4 * gy + m5;
                float x0 = floorf(xin), y0 = floorf(yin);
                float wx = xin - x0, wy = yin - y0;
                int x0i = (int)x0, y0i = (int)y0;
                auto tapf = [&](int yy, int xx) -> float {
                    bool valid = (xx >= 0) && (xx < TSz) && (yy >= 0) && (yy < TSz);
                    int yc = min(max(yy, 0), TSz - 1), xc = min(max(xx, 0), TSz - 1);
                    float v = tp[yc * TSz + xc];
                    return valid ? v : 0.f;
                };
                float v00 = tapf(y0i, x0i),     v01 = tapf(y0i, x0i + 1);
                float v10 = tapf(y0i + 1, x0i), v11 = tapf(y0i + 1, x0i + 1);
                val = v00 * (1.f - wx) * (1.f - wy) + v01 * wx * (1.f - wy) +
                      v10 * (1.f - wx) * wy + v11 * wx * wy;
                to[p] = val;
            }
            tvl[r] = val;
        }
        float mx = -1e30f;
#pragma unroll
        for (int r = 0; r < 7; ++r) {
            int p = tid + r * 256;
            if (p < 1600) mx = fmaxf(mx, dm * tvl[r]);
        }
        mx = blockReduceMax(mx);
        float s = 0.f;
#pragma unroll
        for (int r = 0; r < 7; ++r) {
            int p = tid + r * 256;
            if (p < 1600) s += expf(dm * tvl[r] - mx);
        }
        s = blockReduceSum(s);
        if (tid == 0) { mxs[bkL * 2] = mx; mxs[bkL * 2 + 1] = s; }
    }
}

// ============ log-likelihood, split over 8 pixel-blocks per sample ============
__global__ __launch_bounds__(TPB) void ll_k(const float* __restrict__ x,
                                            const float* __restrict__ tt,
                                            const float* __restrict__ dmv,
                                            const float* __restrict__ mxs,
                                            const float* __restrict__ st,
                                            float* __restrict__ part) {
    const int b = blockIdx.x, sp = blockIdx.y;
    __shared__ float dms[24], mxh[24], sih[24];
    if (threadIdx.x < 24) {
        int bk = b * 24 + threadIdx.x;
        dms[threadIdx.x] = dmv[bk];
        mxh[threadIdx.x] = mxs[bk * 2];
        sih[threadIdx.x] = 1.f / mxs[bk * 2 + 1];
    }
    __syncthreads();
    const float mult = st[b * 2], pw = st[b * 2 + 1];
    const float* xb = x + b * 1600;
    const float* tb = tt + (size_t)b * 24 * 1600;
    float acc = 0.f;
    int p = sp * 200 + threadIdx.x;
    if (threadIdx.x < 200) {
        float xv = xb[p];
        float ssum = 0.f;
        for (int k = 0; k < 24; ++k) {
            float tv = tb[(size_t)k * 1600 + p];
            float dd = xv - tv;
            float g = mult * expf(dd * dd * pw);
            float mixv = expf(dms[k] * tv - mxh[k]) * sih[k];
            ssum += g * mixv;
        }
        acc = logf(ssum);
    }
    acc = blockReduceSum(acc);
    if (threadIdx.x == 0) part[b * 8 + sp] = acc;
}

__global__ void fin_k(const float* __restrict__ part, float* __restrict__ out) {
    float v = 0.f;
#pragma unroll
    for (int q = 0; q < 8; ++q) v += part[threadIdx.x * 8 + q];
#pragma unroll
    for (int o = 32; o > 0; o >>= 1) v += __shfl_down(v, o, 64);
    if (threadIdx.x == 0) out[0] = v * (1.f / 64.f);
}

// ============ launch ============
extern "C" void kernel_launch(void* const* d_in, const int* in_sizes, int n_in,
                              void* d_out, int out_size, void* d_ws, size_t ws_size,
                              hipStream_t stream) {
    const float* x   = (const float*)d_in[0];
    const float* w1  = (const float*)d_in[1];
    const float* b1  = (const float*)d_in[2];
    const float* w2  = (const float*)d_in[3];
    const float* b2  = (const float*)d_in[4];
    const float* w3  = (const float*)d_in[5];
    const float* b3  = (const float*)d_in[6];
    const float* w4  = (const float*)d_in[7];
    const float* b4  = (const float*)d_in[8];
    const float* w5  = (const float*)d_in[9];
    const float* b5  = (const float*)d_in[10];
    const float* tpl = (const float*)d_in[11];
    float* out = (float*)d_out;
    char* W = (char*)d_ws;

    ushort* wt2 = (ushort*)(W + OFFB_W2);
    ushort* wt3 = (ushort*)(W + OFFB_W3);
    ushort* wt4 = (ushort*)(W + OFFB_W4);
    float*  dmv  = (float*)(W + OFFB_DMV);
    float*  ttb  = (float*)(W + OFFB_TT);
    float*  stv  = (float*)(W + OFFB_ST);
    float*  mxs  = (float*)(W + OFFB_MXS);
    float*  part = (float*)(W + OFFB_PART);

    prep_k<<<3 * 3072 + Bn, TPB, 0, stream>>>(w2, w3, w4, x, wt2, wt3, wt4, stv);
    convall_k<<<NBK, 256, 0, stream>>>(x, w1, b1, wt2, b2, wt3, b3, wt4, b4,
                                       w5, b5, tpl, dmv, ttb, mxs, out);
    ll_k<<<dim3(Bn, 8), TPB, 0, stream>>>(x, ttb, dmv, mxs, stv, part);
    fin_k<<<1, 64, 0, stream>>>(part, out);
}

// Round 17
// 189.399 us; speedup vs baseline: 1.2543x; 1.0432x over previous
//
#include <hip/hip_runtime.h>
#include <math.h>

#define TPB 256

typedef __attribute__((ext_vector_type(8))) short s16x8;
typedef __attribute__((ext_vector_type(4))) short s16x4;
typedef __attribute__((ext_vector_type(4))) float f32x4;
typedef unsigned int u32;

constexpr int Bn = 64, Kc = 24, TSz = 11;
constexpr int NBK = Bn * Kc;          // 1536

// ---- workspace offsets (BYTES) ----
constexpr size_t SZW_B    = (size_t)Kc * 36 * 4096 * 2;      // 7,077,888 B/plane
constexpr size_t OFFB_W2  = 0;
constexpr size_t OFFB_W3  = OFFB_W2 + SZW_B;
constexpr size_t OFFB_W4  = OFFB_W3 + SZW_B;
constexpr size_t OFFB_W5  = OFFB_W4 + SZW_B;
constexpr size_t OFFB_DMV = OFFB_W5 + (size_t)Kc * 2048 * 2;
constexpr size_t OFFB_TT  = OFFB_DMV + (size_t)NBK * 4;
constexpr size_t OFFB_ST  = OFFB_TT + (size_t)NBK * 1600 * 4;
constexpr size_t OFFB_MXS = OFFB_ST + 512;
constexpr size_t OFFB_PART= OFFB_MXS + (size_t)NBK * 2 * 4;

// ---- output offsets (floats) ----
constexpr int OUT_OC = 1;                   // input_ocae [B,K,136]
constexpr int OUT_XM = 1 + NBK * 136;
constexpr int OUT_DM = OUT_XM + NBK * 6;

// ============ bf16 helpers ============
__device__ __forceinline__ ushort f2b(float f) {
    union { float f; unsigned u; } c; c.f = f;
    unsigned r = c.u + 0x7fffu + ((c.u >> 16) & 1u);
    return (ushort)(r >> 16);
}
__device__ __forceinline__ float b2f(ushort h) {
    union { unsigned u; float f; } c; c.u = ((unsigned)h) << 16; return c.f;
}

// ============ reductions (256 threads → 4 waves) ============
__device__ __forceinline__ float blockReduceSum(float v) {
    __shared__ float red[4];
    __syncthreads();
#pragma unroll
    for (int o = 32; o > 0; o >>= 1) v += __shfl_down(v, o, 64);
    int lane = threadIdx.x & 63, wv = threadIdx.x >> 6;
    if (lane == 0) red[wv] = v;
    __syncthreads();
    return red[0] + red[1] + red[2] + red[3];
}

__device__ __forceinline__ float blockReduceMax(float v) {
    __shared__ float redm[4];
    __syncthreads();
#pragma unroll
    for (int o = 32; o > 0; o >>= 1) v = fmaxf(v, __shfl_down(v, o, 64));
    int lane = threadIdx.x & 63, wv = threadIdx.x >> 6;
    if (lane == 0) redm[wv] = v;
    __syncthreads();
    return fmaxf(fmaxf(redm[0], redm[1]), fmaxf(redm[2], redm[3]));
}

// ============ merged prep: 3x conv weights + w5 frag + std stats ============
// K=32 frag-major layout: [k][cb][tap] blocks of 4096 ush, inner [n][g8][l16][e8].
// w5t: [k][cb] blocks of 512 ush, inner [g][l16][e8]; element (l16=f, k=cb*32+g*8+e).
__global__ __launch_bounds__(TPB) void prep_k(
    const float* __restrict__ w2, const float* __restrict__ w3,
    const float* __restrict__ w4, const float* __restrict__ w5,
    const float* __restrict__ x,
    ushort* __restrict__ wt2, ushort* __restrict__ wt3,
    ushort* __restrict__ wt4, ushort* __restrict__ wt5,
    float* __restrict__ st) {
    const int bid = blockIdx.x;
    if (bid < 9216) {
        __shared__ float ld[1152];
        const float* w = bid < 3072 ? w2 : (bid < 6144 ? w3 : w4);
        ushort* wt = bid < 3072 ? wt2 : (bid < 6144 ? wt3 : wt4);
        const int kk = (bid % 3072) >> 7, cout = bid & 127;
        const float* src = w + (size_t)(kk * 128 + cout) * 1152;
        for (int i = threadIdx.x; i < 1152; i += TPB) ld[i] = src[i];
        __syncthreads();
        const int n = cout >> 4, l16 = cout & 15;
        for (int e = threadIdx.x; e < 1152; e += TPB) {
            int cb = e / 288, r = e - cb * 288, tap = r >> 5, c32 = r & 31;
            int cin = cb * 32 + c32;
            size_t d = (size_t)((kk * 4 + cb) * 9 + tap) * 4096
                     + n * 512 + (c32 >> 3) * 128 + l16 * 8 + (c32 & 7);
            wt[d] = f2b(ld[cin * 9 + tap]);
        }
    } else if (bid < 9280) {
        const int b = bid - 9216;
        const float* xb = x + b * 1600;
        float s = 0.f, s2 = 0.f;
        for (int p = threadIdx.x; p < 1600; p += TPB) {
            float v = xb[p];
            s += v; s2 += v * v;
        }
        s = blockReduceSum(s);
        s2 = blockReduceSum(s2);
        if (threadIdx.x == 0) {
            float mean = s / 1600.f;
            float var = (s2 - 1600.f * mean * mean) / 1599.f;
            float sd = sqrtf(var);
            st[b * 2] = rsqrtf(sd * 6.283185307179586f);   // mult
            st[b * 2 + 1] = -1.f / (2.f * sd * sd);        // pw
        }
    } else {
        const int kk = bid - 9280;    // w5 frag transpose, one k per block
        for (int e = threadIdx.x; e < 2048; e += TPB) {
            int cb = e >> 9, rem = e & 511;
            int gg = rem >> 7, l16 = (rem >> 3) & 15, ee = e & 7;
            wt5[(size_t)kk * 2048 + e] =
                f2b(w5[(size_t)(kk * 16 + l16) * 128 + cb * 32 + gg * 8 + ee]);
        }
    }
}

// ============ MEGA-KERNEL: conv1..conv4->conv5(MFMA)->head->warp ============
// Round-14 proven structure; cb loops runtime (#pragma unroll 1, I$-compact);
// B rings 3-deep (buffer idx tap%3 static). NEW: phase C writes h4 as bf16
// [pix][cin] stride-136 (same epilogue pattern as phase B); phase D conv5 is
// 4 MFMAs/wave on waves 0-1 (A=h4 rows, B=w5t frags) instead of 51K scalar ops.
__global__ __launch_bounds__(256) void convall_k(
    const float* __restrict__ x, const float* __restrict__ w1,
    const float* __restrict__ b1,
    const ushort* __restrict__ wt2, const float* __restrict__ b2,
    const ushort* __restrict__ wt3, const float* __restrict__ b3,
    const ushort* __restrict__ wt4, const float* __restrict__ b4,
    const ushort* __restrict__ wt5, const float* __restrict__ b5,
    const float* __restrict__ tpl,
    float* __restrict__ dmv, float* __restrict__ tt,
    float* __restrict__ mxs, float* __restrict__ out) {
    __shared__ __align__(16) ushort pool[17680];
    float*  xs  = (float*)pool;
    ushort* As  = pool + 3200;
    ushort* h2L = pool;
    ushort* h3L = pool + 11016;
    ushort* h4b = pool;                          // 25*136 ush, < h3L offset
    float*  outs= (float*)(pool + 6400);
    float*  atts= (float*)(pool + 7200);
    float*  pooled = (float*)(pool + 7264);
    float*  tp  = (float*)(pool + 7400);

    const int bi = blockIdx.x;
    const int xcd = bi & 7, jj = bi >> 3;
    const int k = xcd * 3 + jj % 3, b = jj / 3;  // k-clustered per XCD
    const int bkL = b * 24 + k;
    const int tid = threadIdx.x;
    const int w = tid >> 6, l = tid & 63, l16 = l & 15, g = l >> 4;
    const int mgrp = w >> 1, ngrp = w & 1;

    // ======== phase A: fused conv1+conv2 ========
    {
        constexpr int OP = 81, STR = 40;
        const int sl = tid & 7, p0 = tid >> 3;
        const ushort* wb = wt2 + (size_t)k * 36 * 4096 + ngrp * 2048 + g * 128 + l16 * 8;
        const float* w1k = w1 + (size_t)k * 1152;
        const float* b1k = b1 + k * 128;

        for (int i = tid; i < 400; i += 256)
            ((f32x4*)xs)[i] = ((const f32x4*)(x + b * 1600))[i];

        f32x4 acc[3][4];
#pragma unroll
        for (int m = 0; m < 3; ++m)
#pragma unroll
            for (int n = 0; n < 4; ++n) acc[m][n] = (f32x4)0.f;

        int ibase[3];
#pragma unroll
        for (int m = 0; m < 3; ++m) {
            int row = (mgrp * 3 + m) * 16 + l16;
            row = row < OP ? row : OP - 1;
            int oy = row / 9, ox = row - oy * 9;
            ibase[m] = oy * 38 + ox * 2;
        }

        // conv1 slab writer (runtime cb): weights loaded here
        auto conv1_slab = [&](int cb) {
            float wq[36], bq[4];
            const float* wsrc = w1k + (cb * 32 + sl * 4) * 9;
#pragma unroll
            for (int i2 = 0; i2 < 9; ++i2) ((f32x4*)wq)[i2] = ((const f32x4*)wsrc)[i2];
            *(f32x4*)bq = *(const f32x4*)(b1k + cb * 32 + sl * 4);
            for (int p = p0; p < 361; p += 32) {
                int py = p / 19, px = p - py * 19;
                const float* xb = xs + py * 80 + px * 2;
                float xt[9];
#pragma unroll
                for (int dy = 0; dy < 3; ++dy)
#pragma unroll
                    for (int dx = 0; dx < 3; ++dx) xt[dy * 3 + dx] = xb[dy * 40 + dx];
                s16x4 v;
#pragma unroll
                for (int j2 = 0; j2 < 4; ++j2) {
                    float s2 = bq[j2];
#pragma unroll
                    for (int t9 = 0; t9 < 9; ++t9) s2 += wq[j2 * 9 + t9] * xt[t9];
                    v[j2] = (short)f2b(fmaxf(s2, 0.f));
                }
                *(s16x4*)(As + p * STR + 8 * ((sl >> 1) ^ ((p >> 3) & 1)) + (sl & 1) * 4) = v;
            }
        };

        s16x8 breg[3][4];
        __syncthreads();                         // xs visible
        conv1_slab(0);
#pragma unroll
        for (int n = 0; n < 4; ++n) breg[0][n] = *(const s16x8*)(wb + n * 512);
#pragma unroll
        for (int n = 0; n < 4; ++n) breg[1][n] = *(const s16x8*)(wb + 4096 + n * 512);
        __syncthreads();                         // As ready

#pragma unroll 1
        for (int cb = 0; cb < 4; ++cb) {
#pragma unroll
            for (int tap = 0; tap < 9; ++tap) {
                const int it = cb * 9 + tap;     // runtime; buffer idx tap%3 static
                if (it + 2 < 36) {               // 3-deep ring, prefetch distance 2
                    const ushort* src = wb + (size_t)(it + 2) * 4096;
#pragma unroll
                    for (int n = 0; n < 4; ++n)
                        breg[(tap + 2) % 3][n] = *(const s16x8*)(src + n * 512);
                }
                const int ioff = (tap / 3) * 19 + (tap % 3);
                s16x8 a[3];
#pragma unroll
                for (int m = 0; m < 3; ++m) {
                    int ip = ibase[m] + ioff;
                    a[m] = *(const s16x8*)(As + ip * STR + 8 * (g ^ ((ip >> 3) & 1)));
                }
#pragma unroll
                for (int n = 0; n < 4; ++n)
#pragma unroll
                    for (int m = 0; m < 3; ++m)
                        acc[m][n] = __builtin_amdgcn_mfma_f32_16x16x32_bf16(a[m], breg[tap % 3][n], acc[m][n], 0, 0, 0);
            }
            if (cb < 3) {
                __syncthreads();
                conv1_slab(cb + 1);
                __syncthreads();
            }
        }
        __syncthreads();                         // all As reads done before h2L overwrite
        // epilogue -> h2L (LDS, stride 136)
#pragma unroll
        for (int n = 0; n < 4; ++n) {
            int cout = (ngrp * 4 + n) * 16 + l16;
            float bv = b2[k * 128 + cout];
#pragma unroll
            for (int m = 0; m < 3; ++m)
#pragma unroll
                for (int r = 0; r < 4; ++r) {
                    int row = (mgrp * 3 + m) * 16 + g * 4 + r;
                    if (row < OP)
                        h2L[row * 136 + cout] = f2b(fmaxf(acc[m][n][r] + bv, 0.f));
                }
        }
    }
    __syncthreads();                             // h2L visible

    // ======== phase B: conv3 (9x9 -> 7x7), h2L -> h3L ========
    {
        constexpr int OP = 49;
        const ushort* wb = wt3 + (size_t)k * 36 * 4096 + ngrp * 2048 + g * 128 + l16 * 8;
        s16x8 breg[3][4];
#pragma unroll
        for (int n = 0; n < 4; ++n) breg[0][n] = *(const s16x8*)(wb + n * 512);
#pragma unroll
        for (int n = 0; n < 4; ++n) breg[1][n] = *(const s16x8*)(wb + 4096 + n * 512);

        f32x4 acc[2][4];
#pragma unroll
        for (int m = 0; m < 2; ++m)
#pragma unroll
            for (int n = 0; n < 4; ++n) acc[m][n] = (f32x4)0.f;

        int ibase[2];
#pragma unroll
        for (int m = 0; m < 2; ++m) {
            int row = (mgrp * 2 + m) * 16 + l16;
            row = row < OP ? row : OP - 1;
            int oy = row / 7, ox = row - oy * 7;
            ibase[m] = oy * 9 + ox;
        }
#pragma unroll 1
        for (int cb = 0; cb < 4; ++cb)
#pragma unroll
            for (int tap = 0; tap < 9; ++tap) {
                const int it = cb * 9 + tap;
                if (it + 2 < 36) {
                    const ushort* src = wb + (size_t)(it + 2) * 4096;
#pragma unroll
                    for (int n = 0; n < 4; ++n)
                        breg[(tap + 2) % 3][n] = *(const s16x8*)(src + n * 512);
                }
                const int ioff = (tap / 3) * 9 + (tap % 3);
                s16x8 a[2];
#pragma unroll
                for (int m = 0; m < 2; ++m)
                    a[m] = *(const s16x8*)(h2L + (ibase[m] + ioff) * 136 + cb * 32 + g * 8);
#pragma unroll
                for (int n = 0; n < 4; ++n)
#pragma unroll
                    for (int m = 0; m < 2; ++m)
                        acc[m][n] = __builtin_amdgcn_mfma_f32_16x16x32_bf16(a[m], breg[tap % 3][n], acc[m][n], 0, 0, 0);
            }
        // epilogue -> h3L (disjoint from h2L)
#pragma unroll
        for (int n = 0; n < 4; ++n) {
            int cout = (ngrp * 4 + n) * 16 + l16;
            float bv = b3[k * 128 + cout];
#pragma unroll
            for (int m = 0; m < 2; ++m)
#pragma unroll
                for (int r = 0; r < 4; ++r) {
                    int row = (mgrp * 2 + m) * 16 + g * 4 + r;
                    if (row < OP)
                        h3L[row * 136 + cout] = f2b(fmaxf(acc[m][n][r] + bv, 0.f));
                }
        }
    }
    __syncthreads();                             // h3L visible (h2L dead)

    // ======== phase C: conv4 (7x7 -> 5x5), h3L -> h4b (bf16, stride 136) ========
    {
        constexpr int OP = 25;
        const ushort* wb = wt4 + (size_t)k * 36 * 4096 + ngrp * 2048 + g * 128 + l16 * 8;
        s16x8 breg[3][4];
#pragma unroll
        for (int n = 0; n < 4; ++n) breg[0][n] = *(const s16x8*)(wb + n * 512);
#pragma unroll
        for (int n = 0; n < 4; ++n) breg[1][n] = *(const s16x8*)(wb + 4096 + n * 512);

        f32x4 acc[4];
#pragma unroll
        for (int n = 0; n < 4; ++n) acc[n] = (f32x4)0.f;

        int ibase;
        {
            int row = mgrp * 16 + l16;
            row = row < OP ? row : OP - 1;
            int oy = row / 5, ox = row - oy * 5;
            ibase = oy * 7 + ox;
        }
#pragma unroll 1
        for (int cb = 0; cb < 4; ++cb)
#pragma unroll
            for (int tap = 0; tap < 9; ++tap) {
                const int it = cb * 9 + tap;
                if (it + 2 < 36) {
                    const ushort* src = wb + (size_t)(it + 2) * 4096;
#pragma unroll
                    for (int n = 0; n < 4; ++n)
                        breg[(tap + 2) % 3][n] = *(const s16x8*)(src + n * 512);
                }
                const int ioff = (tap / 3) * 7 + (tap % 3);
                s16x8 a = *(const s16x8*)(h3L + (ibase + ioff) * 136 + cb * 32 + g * 8);
#pragma unroll
                for (int n = 0; n < 4; ++n)
                    acc[n] = __builtin_amdgcn_mfma_f32_16x16x32_bf16(a, breg[tap % 3][n], acc[n], 0, 0, 0);
            }
        // epilogue -> h4b[row*136 + cout] bf16 (disjoint from h3L: 3400 < 11016)
#pragma unroll
        for (int n = 0; n < 4; ++n) {
            int cout = (ngrp * 4 + n) * 16 + l16;
            float bv = b4[k * 128 + cout];
#pragma unroll
            for (int r = 0; r < 4; ++r) {
                int row = mgrp * 16 + g * 4 + r;
                if (row < OP)
                    h4b[row * 136 + cout] = f2b(fmaxf(acc[n][r] + bv, 0.f));
            }
        }
    }
    __syncthreads();                             // h4b visible

    // ======== phase D: conv5 via MFMA (25x16x128) + attention + pooling ========
    {
        // A = h4b rows (pix, M=25 over 2 m-frags), B = w5t frags (N=16 f), K=128.
        // Waves 0-1 each own one m-frag: 4 MFMAs/wave.
        const ushort* wb5 = wt5 + (size_t)k * 2048 + g * 128 + l16 * 8;
        if (w < 2) {
            f32x4 acc5 = (f32x4)0.f;
            int prow = w * 16 + l16;
            prow = prow < 25 ? prow : 24;        // clamp pad rows
#pragma unroll
            for (int cb = 0; cb < 4; ++cb) {
                s16x8 a = *(const s16x8*)(h4b + prow * 136 + cb * 32 + g * 8);
                s16x8 bb = *(const s16x8*)(wb5 + cb * 512);
                acc5 = __builtin_amdgcn_mfma_f32_16x16x32_bf16(a, bb, acc5, 0, 0, 0);
            }
            float bv5 = b5[k * 16 + l16];        // f = l16
#pragma unroll
            for (int r = 0; r < 4; ++r) {
                int pix = w * 16 + g * 4 + r;
                if (pix < 25) outs[l16 * 25 + pix] = acc5[r] + bv5;
            }
        }
    }
    __syncthreads();
    if (tid < 25) {
        int y5 = tid / 5;
        const float* row = outs + 15 * 25 + y5 * 5;
        float mx = row[0];
#pragma unroll
        for (int j = 1; j < 5; ++j) mx = fmaxf(mx, row[j]);
        float ssum = 0.f;
#pragma unroll
        for (int j = 0; j < 5; ++j) ssum += expf(row[j] - mx);
        atts[tid] = expf(outs[15 * 25 + tid] - mx) / ssum;
    }
    __syncthreads();
    if (tid < 15) {
        float s = 0.f;
        const float* row = outs + tid * 25;
#pragma unroll
        for (int p = 0; p < 25; ++p) s += row[p] * atts[p];
        pooled[tid] = s;
    }
    __syncthreads();                             // pooled visible to all
    float* oc = out + OUT_OC + (size_t)bkL * 136;
    if (tid < 6) {
        float v = fmaxf(pooled[tid], 0.f);
        oc[1 + tid] = v;
        out[OUT_XM + bkL * 6 + tid] = v;
    } else if (tid == 6) {
        float d = 1.f / (1.f + expf(-pooled[6]));
        dmv[bkL] = d;
        oc[0] = d;
        out[OUT_DM + bkL] = d;
    } else if (tid >= 7 && tid < 15) {
        oc[128 + tid - 7] = fmaxf(pooled[tid], 0.f);
    }
    for (int t = tid; t < 121; t += 256) oc[7 + t] = tpl[k * 121 + t];

    // ======== phase E: affine warp + bilinear TS->40x40 + mix softmax stats ========
    for (int i = tid; i < 121; i += 256) tp[i] = tpl[k * 121 + i];
    {
        const float D2R = 0.017453292519943295f;
        float ang = fmaxf(pooled[0], 0.f) * D2R;
        float txp = fmaxf(pooled[1], 0.f), typ = fmaxf(pooled[2], 0.f);
        float sc  = fmaxf(fmaxf(pooled[3], 0.f), 1e-2f);
        float shx = fmaxf(pooled[4], 0.f) * D2R;
        float shy = fmaxf(pooled[5], 0.f) * D2R;
        float dm  = 1.f / (1.f + expf(-pooled[6]));
        float cams = cosf(ang - shy), sams = sinf(ang - shy);
        float cshy = cosf(shy), tshx = tanf(shx);
        float av = cams / cshy;
        float bv = -cams * tshx / cshy - sinf(ang);
        float cv = sams / cshy;
        float dv = -sams * tshx / cshy + cosf(ang);
        float m0 = dv / sc, m1 = -bv / sc, m3 = -cv / sc, m4 = av / sc;
        float m2 = m0 * (-5.f - txp) + m1 * (-5.f - typ) + 5.f;
        float m5 = m3 * (-5.f - txp) + m4 * (-5.f - typ) + 5.f;
        __syncthreads();                         // tp visible
        float* to = tt + (size_t)bkL * 1600;
        float tvl[7];
#pragma unroll
        for (int r = 0; r < 7; ++r) {
            int p = tid + r * 256;
            float val = 0.f;
            if (p < 1600) {
                int i = p / 40, jx = p - (p / 40) * 40;
                float gx = (jx + 0.5f) * (11.f / 40.f) - 0.5f;
                float gy = (i + 0.5f) * (11.f / 40.f) - 0.5f;
                float xin = m0 * gx + m1 * gy + m2;
                float yin = m3 * gx + m4 * gy + m5;
                float x0 = floorf(xin), y0 = floorf(yin);
                float wx = xin - x0, wy = yin - y0;
                int x0i = (int)x0, y0i = (int)y0;
                auto tapf = [&](int yy, int xx) -> float {
                    bool valid = (xx >= 0) && (xx < TSz) && (yy >= 0) && (yy < TSz);
                    int yc = min(max(yy, 0), TSz - 1), xc = min(max(xx, 0), TSz - 1);
                    float v = tp[yc * TSz + xc];
                    return valid ? v : 0.f;
                };
                float v00 = tapf(y0i, x0i),     v01 = tapf(y0i, x0i + 1);
                float v10 = tapf(y0i + 1, x0i), v11 = tapf(y0i + 1, x0i + 1);
                val = v00 * (1.f - wx) * (1.f - wy) + v01 * wx * (1.f - wy) +
                      v10 * (1.f - wx) * wy + v11 * wx * wy;
                to[p] = val;
            }
            tvl[r] = val;
        }
        float mx = -1e30f;
#pragma unroll
        for (int r = 0; r < 7; ++r) {
            int p = tid + r * 256;
            if (p < 1600) mx = fmaxf(mx, dm * tvl[r]);
        }
        mx = blockReduceMax(mx);
        float s = 0.f;
#pragma unroll
        for (int r = 0; r < 7; ++r) {
            int p = tid + r * 256;
            if (p < 1600) s += expf(dm * tvl[r] - mx);
        }
        s = blockReduceSum(s);
        if (tid == 0) { mxs[bkL * 2] = mx; mxs[bkL * 2 + 1] = s; }
    }
}

// ============ log-likelihood, split over 8 pixel-blocks per sample ============
__global__ __launch_bounds__(TPB) void ll_k(const float* __restrict__ x,
                                            const float* __restrict__ tt,
                                            const float* __restrict__ dmv,
                                            const float* __restrict__ mxs,
                                            const float* __restrict__ st,
                                            float* __restrict__ part) {
    const int b = blockIdx.x, sp = blockIdx.y;
    __shared__ float dms[24], mxh[24], sih[24];
    if (threadIdx.x < 24) {
        int bk = b * 24 + threadIdx.x;
        dms[threadIdx.x] = dmv[bk];
        mxh[threadIdx.x] = mxs[bk * 2];
        sih[threadIdx.x] = 1.f / mxs[bk * 2 + 1];
    }
    __syncthreads();
    const float mult = st[b * 2], pw = st[b * 2 + 1];
    const float* xb = x + b * 1600;
    const float* tb = tt + (size_t)b * 24 * 1600;
    float acc = 0.f;
    int p = sp * 200 + threadIdx.x;
    if (threadIdx.x < 200) {
        float xv = xb[p];
        float ssum = 0.f;
        for (int k = 0; k < 24; ++k) {
            float tv = tb[(size_t)k * 1600 + p];
            float dd = xv - tv;
            float g = mult * expf(dd * dd * pw);
            float mixv = expf(dms[k] * tv - mxh[k]) * sih[k];
            ssum += g * mixv;
        }
        acc = logf(ssum);
    }
    acc = blockReduceSum(acc);
    if (threadIdx.x == 0) part[b * 8 + sp] = acc;
}

__global__ void fin_k(const float* __restrict__ part, float* __restrict__ out) {
    float v = 0.f;
#pragma unroll
    for (int q = 0; q < 8; ++q) v += part[threadIdx.x * 8 + q];
#pragma unroll
    for (int o = 32; o > 0; o >>= 1) v += __shfl_down(v, o, 64);
    if (threadIdx.x == 0) out[0] = v * (1.f / 64.f);
}

// ============ launch ============
extern "C" void kernel_launch(void* const* d_in, const int* in_sizes, int n_in,
                              void* d_out, int out_size, void* d_ws, size_t ws_size,
                              hipStream_t stream) {
    const float* x   = (const float*)d_in[0];
    const float* w1  = (const float*)d_in[1];
    const float* b1  = (const float*)d_in[2];
    const float* w2  = (const float*)d_in[3];
    const float* b2  = (const float*)d_in[4];
    const float* w3  = (const float*)d_in[5];
    const float* b3  = (const float*)d_in[6];
    const float* w4  = (const float*)d_in[7];
    const float* b4  = (const float*)d_in[8];
    const float* w5  = (const float*)d_in[9];
    const float* b5  = (const float*)d_in[10];
    const float* tpl = (const float*)d_in[11];
    float* out = (float*)d_out;
    char* W = (char*)d_ws;

    ushort* wt2 = (ushort*)(W + OFFB_W2);
    ushort* wt3 = (ushort*)(W + OFFB_W3);
    ushort* wt4 = (ushort*)(W + OFFB_W4);
    ushort* wt5 = (ushort*)(W + OFFB_W5);
    float*  dmv  = (float*)(W + OFFB_DMV);
    float*  ttb  = (float*)(W + OFFB_TT);
    float*  stv  = (float*)(W + OFFB_ST);
    float*  mxs  = (float*)(W + OFFB_MXS);
    float*  part = (float*)(W + OFFB_PART);

    prep_k<<<9280 + Kc, TPB, 0, stream>>>(w2, w3, w4, w5, x, wt2, wt3, wt4, wt5, stv);
    convall_k<<<NBK, 256, 0, stream>>>(x, w1, b1, wt2, b2, wt3, b3, wt4, b4,
                                       wt5, b5, tpl, dmv, ttb, mxs, out);
    ll_k<<<dim3(Bn, 8), TPB, 0, stream>>>(x, ttb, dmv, mxs, stv, part);
    fin_k<<<1, 64, 0, stream>>>(part, out);
}